// Round 2
// baseline (284.056 us; speedup 1.0000x reference)
//
#include <hip/hip_runtime.h>
#include <stdint.h>

#define DEV __device__ __forceinline__

typedef __bf16 bf16x8 __attribute__((ext_vector_type(8)));
typedef float f32x4 __attribute__((ext_vector_type(4)));
typedef unsigned short u16;
typedef u16 u16x8 __attribute__((ext_vector_type(8)));

constexpr int Bb = 8, Ss = 512, Ee = 1024, Hh = 16;
constexpr int BS = Bb * Ss;     // 4096
constexpr int NH2 = 32;         // D/2

DEV u16 f2bf(float f) {
  union { float f; uint32_t u; } v; v.f = f;
  return (u16)((v.u + 0x7FFFu + ((v.u >> 16) & 1u)) >> 16);
}
DEV float bf2f(u16 h) {
  union { uint32_t u; float f; } v; v.u = ((uint32_t)h) << 16;
  return v.f;
}
DEV bf16x8 ldsbf8(const u16* p) {
  u16x8 u = *(const u16x8*)p;
  return __builtin_bit_cast(bf16x8, u);
}
DEV f32x4 mfma16(bf16x8 a, bf16x8 b, f32x4 c) {
  return __builtin_amdgcn_mfma_f32_16x16x32_bf16(a, b, c, 0, 0, 0);
}
DEV u16x8 cvt8(float4 v0, float4 v1) {
  u16x8 o;
  o[0] = f2bf(v0.x); o[1] = f2bf(v0.y); o[2] = f2bf(v0.z); o[3] = f2bf(v0.w);
  o[4] = f2bf(v1.x); o[5] = f2bf(v1.y); o[6] = f2bf(v1.z); o[7] = f2bf(v1.w);
  return o;
}

// ---------------- GEMM: C[m,f] = sum_e A[m,e]*W[f,e] + bias[f] ----------------
// 128x128 tile, BK=64, 4 waves (2x2 of 64x64), mfma 16x16x32 bf16.
// A either fp32 (converted during staging) or bf16; W always fp32.
// LDS rows are 128B: XOR-swizzle 16B chunks by (row&7) to avoid bank conflicts.
template<bool A_BF16, bool OUT_F32>
DEV void gemm_core(const void* __restrict__ A_, const float* __restrict__ W,
                   const float* __restrict__ bias, void* __restrict__ out) {
  constexpr int K = Ee, N = Ee;
  __shared__ u16 sA[128 * 64], sB[128 * 64];
  int tid = threadIdx.x;
  int lane = tid & 63, wid = tid >> 6;
  int lr = lane & 15, lh = lane >> 4;
  int m0 = blockIdx.x * 128, n0 = blockIdx.y * 128;
  int wm = (wid >> 1) * 64, wn = (wid & 1) * 64;
  f32x4 acc[4][4];
#pragma unroll
  for (int a = 0; a < 4; ++a)
#pragma unroll
    for (int q = 0; q < 4; ++q) acc[a][q] = f32x4{0.f, 0.f, 0.f, 0.f};

  for (int k0 = 0; k0 < K; k0 += 64) {
    __syncthreads();
#pragma unroll
    for (int j = 0; j < 4; ++j) {
      int c = tid + j * 256;
      int r = c >> 3, p = c & 7;
      int sl = (p ^ (r & 7)) * 8;
      size_t aoff = (size_t)(m0 + r) * K + k0 + p * 8;
      u16x8 av;
      if constexpr (A_BF16) {
        av = *(const u16x8*)((const u16*)A_ + aoff);
      } else {
        const float4* ap = (const float4*)((const float*)A_ + aoff);
        av = cvt8(ap[0], ap[1]);
      }
      *(u16x8*)(&sA[r * 64 + sl]) = av;
      size_t woff = (size_t)(n0 + r) * K + k0 + p * 8;
      const float4* wp = (const float4*)(W + woff);
      *(u16x8*)(&sB[r * 64 + sl]) = cvt8(wp[0], wp[1]);
    }
    __syncthreads();
#pragma unroll
    for (int ks = 0; ks < 2; ++ks) {
      bf16x8 af[4], bfv[4];
#pragma unroll
      for (int t = 0; t < 4; ++t) {
        int ra = wm + t * 16 + lr;
        af[t] = ldsbf8(&sA[ra * 64 + ((ks * 4 + lh) ^ (lr & 7)) * 8]);
        int rb = wn + t * 16 + lr;
        bfv[t] = ldsbf8(&sB[rb * 64 + ((ks * 4 + lh) ^ (lr & 7)) * 8]);
      }
#pragma unroll
      for (int mt = 0; mt < 4; ++mt)
#pragma unroll
        for (int nt = 0; nt < 4; ++nt)
          acc[mt][nt] = mfma16(af[mt], bfv[nt], acc[mt][nt]);
    }
  }
  // epilogue: C/D layout col=lane&15, row=(lane>>4)*4+i
#pragma unroll
  for (int nt = 0; nt < 4; ++nt) {
    int col = n0 + wn + nt * 16 + lr;
    float bv = bias[col];
#pragma unroll
    for (int mt = 0; mt < 4; ++mt) {
#pragma unroll
      for (int i = 0; i < 4; ++i) {
        int row = m0 + wm + mt * 16 + lh * 4 + i;
        float v = acc[mt][nt][i] + bv;
        if constexpr (OUT_F32) ((float*)out)[(size_t)row * N + col] = v;
        else ((u16*)out)[(size_t)row * N + col] = f2bf(v);
      }
    }
  }
}

__global__ __launch_bounds__(256) void gemm_qkv(
    const float* xq, const float* xk, const float* xv,
    const float* wq, const float* wk, const float* wv,
    const float* bq_, const float* bk_, const float* bv_,
    u16* lq, u16* lk, u16* lv) {
  int z = blockIdx.z;
  const float* A = z == 0 ? xq : (z == 1 ? xk : xv);
  const float* W = z == 0 ? wq : (z == 1 ? wk : wv);
  const float* bias = z == 0 ? bq_ : (z == 1 ? bk_ : bv_);
  u16* out = z == 0 ? lq : (z == 1 ? lk : lv);
  gemm_core<false, false>(A, W, bias, out);
}

__global__ __launch_bounds__(256) void gemm_fin(
    const u16* ctx, const float* wo, const float* bo_, float* out) {
  gemm_core<true, true>(ctx, wo, bo_, out);
}

// ---------------- RoPE + L2 norm + pack to (B,H,S,D) bf16 ----------------
__global__ __launch_bounds__(256) void rope_pack(
    const u16* __restrict__ lq, const u16* __restrict__ lk,
    const float* __restrict__ cosT, const float* __restrict__ sinT,
    u16* __restrict__ qh, u16* __restrict__ kh) {
  int wid = threadIdx.x >> 6, lane = threadIdx.x & 63;
  int widx = blockIdx.x * 4 + wid;          // (b*S + s)*H + h
  const u16* src = blockIdx.y ? lk : lq;
  u16* dst = blockIdx.y ? kh : qh;
  int h = widx & (Hh - 1);
  int s = (widx >> 4) & (Ss - 1);
  int b = widx >> 13;
  float t = bf2f(src[(size_t)widx * 64 + lane]);
  int i = lane >> 1;
  float c = cosT[s * NH2 + i], sn = sinT[s * NH2 + i];
  float pr = __shfl_xor(t, 1);
  float r = (lane & 1) ? (pr * sn + t * c) : (t * c - pr * sn);
  float ss = r * r;
#pragma unroll
  for (int m = 1; m < 64; m <<= 1) ss += __shfl_xor(ss, m);
  r = r / fmaxf(sqrtf(ss), 1e-12f);
  dst[(((size_t)b * Hh + h) * Ss + s) * 64 + lane] = f2bf(r);
}

// ---------------- V pack: (B,S,H,D) -> (B,H,D,S) bf16 ----------------
__global__ __launch_bounds__(256) void v_pack(const u16* __restrict__ vlin, u16* __restrict__ vT) {
  __shared__ u16 tile[64][72];
  int sb = blockIdx.x * 64, h = blockIdx.y, b = blockIdx.z;
  int tid = threadIdx.x;
#pragma unroll
  for (int j = 0; j < 2; ++j) {
    int c = tid + j * 256;
    int r = c >> 3, p = c & 7;
    *(u16x8*)(&tile[r][p * 8]) =
        *(const u16x8*)(vlin + ((size_t)(b * Ss + sb + r)) * Ee + h * 64 + p * 8);
  }
  __syncthreads();
#pragma unroll
  for (int j = 0; j < 2; ++j) {
    int c = tid + j * 256;
    int d = c >> 3, so = (c & 7) * 8;
    u16x8 o;
#pragma unroll
    for (int jj = 0; jj < 8; ++jj) o[jj] = tile[so + jj][d];
    *(u16x8*)(vT + (((size_t)(b * Hh + h)) * 64 + d) * Ss + sb + so) = o;
  }
}

// ---------------- fused flash attention per (b,h,qblock) ----------------
__global__ __launch_bounds__(256) void attn_k(
    const u16* __restrict__ qh, const u16* __restrict__ kh, const u16* __restrict__ vT,
    const float* __restrict__ temp, u16* __restrict__ ctx) {
  __shared__ u16 sQ[64 * 64], sK[64 * 64], sV[64 * 64];
  __shared__ u16 sP[4][16 * 64];
  int tid = threadIdx.x, lane = tid & 63, wid = tid >> 6;
  int lr = lane & 15, lh = lane >> 4;
  int qb = blockIdx.x, h = blockIdx.y, b = blockIdx.z;
  float T = temp[0];
  size_t bh = (size_t)b * Hh + h;
  const u16* Qg = qh + (bh * Ss + qb * 64) * 64;
  const u16* Kg = kh + bh * Ss * 64;
  const u16* Vg = vT + bh * 64 * Ss;

#pragma unroll
  for (int j = 0; j < 2; ++j) {
    int c = tid + j * 256;
    int r = c >> 3, p = c & 7;
    *(u16x8*)(&sQ[r * 64 + (p ^ (r & 7)) * 8]) = *(const u16x8*)(Qg + c * 8);
  }
  __syncthreads();
  bf16x8 qf[2];
  {
    int rq = wid * 16 + lr;
    qf[0] = ldsbf8(&sQ[rq * 64 + ((0 + lh) ^ (lr & 7)) * 8]);
    qf[1] = ldsbf8(&sQ[rq * 64 + ((4 + lh) ^ (lr & 7)) * 8]);
  }
  f32x4 o[4];
#pragma unroll
  for (int nt = 0; nt < 4; ++nt) o[nt] = f32x4{0.f, 0.f, 0.f, 0.f};
  float mrow[4] = {-1e30f, -1e30f, -1e30f, -1e30f};
  float lrow[4] = {0.f, 0.f, 0.f, 0.f};
  u16* sPw = sP[wid];

  for (int kb = 0; kb < Ss / 64; ++kb) {
    __syncthreads();
    const u16* Kt = Kg + (size_t)kb * 64 * 64;
#pragma unroll
    for (int j = 0; j < 2; ++j) {
      int c = tid + j * 256;
      int r = c >> 3, p = c & 7;
      int sl = (p ^ (r & 7)) * 8;
      *(u16x8*)(&sK[r * 64 + sl]) = *(const u16x8*)(Kt + c * 8);
      *(u16x8*)(&sV[r * 64 + sl]) = *(const u16x8*)(Vg + (size_t)r * Ss + kb * 64 + p * 8);
    }
    __syncthreads();
    f32x4 sc[4];
#pragma unroll
    for (int nt = 0; nt < 4; ++nt) sc[nt] = f32x4{0.f, 0.f, 0.f, 0.f};
#pragma unroll
    for (int ks = 0; ks < 2; ++ks)
#pragma unroll
      for (int nt = 0; nt < 4; ++nt) {
        int rk = nt * 16 + lr;
        bf16x8 kf = ldsbf8(&sK[rk * 64 + ((ks * 4 + lh) ^ (lr & 7)) * 8]);
        sc[nt] = mfma16(qf[ks], kf, sc[nt]);
      }
    float mb[4], mn[4], scl[4], psum[4];
#pragma unroll
    for (int nt = 0; nt < 4; ++nt)
#pragma unroll
      for (int i = 0; i < 4; ++i) sc[nt][i] *= T;
#pragma unroll
    for (int i = 0; i < 4; ++i) {
      mb[i] = fmaxf(fmaxf(sc[0][i], sc[1][i]), fmaxf(sc[2][i], sc[3][i]));
#pragma unroll
      for (int m = 1; m < 16; m <<= 1) mb[i] = fmaxf(mb[i], __shfl_xor(mb[i], m));
      mn[i] = fmaxf(mrow[i], mb[i]);
      scl[i] = __expf(mrow[i] - mn[i]);
      psum[i] = 0.f;
    }
#pragma unroll
    for (int nt = 0; nt < 4; ++nt)
#pragma unroll
      for (int i = 0; i < 4; ++i) {
        float p = __expf(sc[nt][i] - mn[i]);
        psum[i] += p;
        int kk = nt * 16 + lr;
        int rowp = lh * 4 + i;
        sPw[rowp * 64 + ((kk >> 3) ^ (rowp & 7)) * 8 + (kk & 7)] = f2bf(p);
      }
#pragma unroll
    for (int i = 0; i < 4; ++i) {
#pragma unroll
      for (int m = 1; m < 16; m <<= 1) psum[i] += __shfl_xor(psum[i], m);
      lrow[i] = lrow[i] * scl[i] + psum[i];
      mrow[i] = mn[i];
    }
#pragma unroll
    for (int nt = 0; nt < 4; ++nt)
#pragma unroll
      for (int i = 0; i < 4; ++i) o[nt][i] *= scl[i];
    // PV
#pragma unroll
    for (int ks = 0; ks < 2; ++ks) {
      bf16x8 pf = ldsbf8(&sPw[lr * 64 + ((ks * 4 + lh) ^ (lr & 7)) * 8]);
#pragma unroll
      for (int nt = 0; nt < 4; ++nt) {
        int dv = nt * 16 + lr;
        bf16x8 vf = ldsbf8(&sV[dv * 64 + ((ks * 4 + lh) ^ (lr & 7)) * 8]);
        o[nt] = mfma16(pf, vf, o[nt]);
      }
    }
  }
#pragma unroll
  for (int nt = 0; nt < 4; ++nt) {
    int d = nt * 16 + lr;
#pragma unroll
    for (int i = 0; i < 4; ++i) {
      int row = qb * 64 + wid * 16 + lh * 4 + i;
      float val = o[nt][i] / lrow[i];
      ctx[((size_t)b * Ss + row) * Ee + h * 64 + d] = f2bf(val);
    }
  }
}

// ---------------- launcher ----------------
extern "C" void kernel_launch(void* const* d_in, const int* in_sizes, int n_in,
                              void* d_out, int out_size, void* d_ws, size_t ws_size,
                              hipStream_t stream) {
  const float* x_q = (const float*)d_in[0];
  const float* x_k = (const float*)d_in[1];
  const float* x_v = (const float*)d_in[2];
  const float* Wq = (const float*)d_in[3];
  const float* bq = (const float*)d_in[4];
  const float* Wk = (const float*)d_in[5];
  const float* bk = (const float*)d_in[6];
  const float* Wv = (const float*)d_in[7];
  const float* bv = (const float*)d_in[8];
  const float* Wo = (const float*)d_in[9];
  const float* bo = (const float*)d_in[10];
  const float* temp = (const float*)d_in[11];
  const float* cosT = (const float*)d_in[12];
  const float* sinT = (const float*)d_in[13];

  char* ws = (char*)d_ws;
  constexpr size_t MB = 1ull << 20;
  // Stream-ordered buffer reuse; peak footprint 40 MiB.
  u16* LQ = (u16*)(ws + 0 * MB);    // q_lin  (B,S,E) bf16, 8 MiB
  u16* LK = (u16*)(ws + 8 * MB);    // k_lin
  u16* LV = (u16*)(ws + 16 * MB);   // v_lin
  u16* QH = (u16*)(ws + 24 * MB);   // q (B,H,S,D) after rope+norm
  u16* KH = (u16*)(ws + 32 * MB);   // k (B,H,S,D)
  u16* VT = (u16*)(ws + 0 * MB);    // v^T (B,H,D,S) — reuses LQ (dead after rope)
  u16* CTX = (u16*)(ws + 8 * MB);   // attention output — reuses LK (dead after rope)

  gemm_qkv<<<dim3(BS / 128, Ee / 128, 3), 256, 0, stream>>>(
      x_q, x_k, x_v, Wq, Wk, Wv, bq, bk, bv, LQ, LK, LV);
  rope_pack<<<dim3(Bb * Ss * Hh / 4, 2), 256, 0, stream>>>(LQ, LK, cosT, sinT, QH, KH);
  v_pack<<<dim3(Ss / 64, Hh, Bb), 256, 0, stream>>>(LV, VT);
  attn_k<<<dim3(Ss / 64, Hh, Bb), 256, 0, stream>>>(QH, KH, VT, temp, CTX);
  gemm_fin<<<dim3(BS / 128, Ee / 128), 256, 0, stream>>>(CTX, Wo, bo, (float*)d_out);
}

// Round 3
// 224.648 us; speedup vs baseline: 1.2644x; 1.2644x over previous
//
#include <hip/hip_runtime.h>
#include <stdint.h>

#define DEV __device__ __forceinline__

typedef __bf16 bf16x8 __attribute__((ext_vector_type(8)));
typedef float f32x4 __attribute__((ext_vector_type(4)));
typedef unsigned short u16;
typedef u16 u16x8 __attribute__((ext_vector_type(8)));
typedef u16 u16x4 __attribute__((ext_vector_type(4)));
typedef __attribute__((address_space(3))) uint8_t lds8;
typedef __attribute__((address_space(1))) const uint8_t glb8;

constexpr int Bb = 8, Ss = 512, Ee = 1024, Hh = 16;
constexpr int BS = Bb * Ss;     // 4096

DEV u16 f2bf(float f) {
  union { float f; uint32_t u; } v; v.f = f;
  return (u16)((v.u + 0x7FFFu + ((v.u >> 16) & 1u)) >> 16);
}
DEV bf16x8 ldsbf8(const u16* p) {
  u16x8 u = *(const u16x8*)p;
  return __builtin_bit_cast(bf16x8, u);
}
DEV f32x4 mfma16(bf16x8 a, bf16x8 b, f32x4 c) {
  return __builtin_amdgcn_mfma_f32_16x16x32_bf16(a, b, c, 0, 0, 0);
}

// ---------------- fp32 -> bf16 conversion (one pass for all operands) ----------------
struct ConvArgs {
  const float* s[7];
  u16* d[7];
  int n[7];
};

__global__ __launch_bounds__(256) void convert_k(ConvArgs a) {
  int z = blockIdx.y;
  int base = (blockIdx.x * 256 + threadIdx.x) * 8;
  if (base >= a.n[z]) return;
  const float4* sp = (const float4*)(a.s[z] + base);
  float4 v0 = sp[0], v1 = sp[1];
  u16x8 o;
  o[0] = f2bf(v0.x); o[1] = f2bf(v0.y); o[2] = f2bf(v0.z); o[3] = f2bf(v0.w);
  o[4] = f2bf(v1.x); o[5] = f2bf(v1.y); o[6] = f2bf(v1.z); o[7] = f2bf(v1.w);
  *(u16x8*)(a.d[z] + base) = o;
}

// ---------------- GEMM main loop: 128x128 tile, BK=64, global_load_lds staging ----
// LDS chunk (r, sl) holds global 16B chunk (r, p) with sl = p ^ (r&7)  (XOR swizzle
// applied by pre-swizzling the per-lane GLOBAL source address; LDS dest is linear —
// global_load_lds writes base + lane*16).
DEV void gemm_main(const u16* __restrict__ A, const u16* __restrict__ W,
                   f32x4 (&acc)[4][4]) {
  constexpr int K = Ee;
  __shared__ u16 sA[128 * 64], sB[128 * 64];
  const int tid = threadIdx.x, lane = tid & 63, wid = tid >> 6;
  const int lr = lane & 15, lh = lane >> 4;
  const int m0 = blockIdx.x * 128, n0 = blockIdx.y * 128;
  const int wm = (wid >> 1) * 64, wn = (wid & 1) * 64;
#pragma unroll
  for (int a = 0; a < 4; ++a)
#pragma unroll
    for (int q = 0; q < 4; ++q) acc[a][q] = f32x4{0.f, 0.f, 0.f, 0.f};

  for (int k0 = 0; k0 < K; k0 += 64) {
    __syncthreads();
#pragma unroll
    for (int j = 0; j < 4; ++j) {
      int c0 = wid * 256 + j * 64;          // wave-uniform chunk base
      int c = c0 + lane;
      int r = c >> 3, p = (c & 7) ^ (r & 7);
      const u16* ga = A + (size_t)(m0 + r) * K + k0 + p * 8;
      const u16* gb = W + (size_t)(n0 + r) * K + k0 + p * 8;
      __builtin_amdgcn_global_load_lds((glb8*)ga, (lds8*)&sA[c0 * 8], 16, 0, 0);
      __builtin_amdgcn_global_load_lds((glb8*)gb, (lds8*)&sB[c0 * 8], 16, 0, 0);
    }
    __syncthreads();   // compiler emits vmcnt(0) drain before barrier
#pragma unroll
    for (int ks = 0; ks < 2; ++ks) {
      bf16x8 af[4], bfv[4];
#pragma unroll
      for (int t = 0; t < 4; ++t) {
        af[t] = ldsbf8(&sA[(wm + t * 16 + lr) * 64 + ((ks * 4 + lh) ^ (lr & 7)) * 8]);
        bfv[t] = ldsbf8(&sB[(wn + t * 16 + lr) * 64 + ((ks * 4 + lh) ^ (lr & 7)) * 8]);
      }
#pragma unroll
      for (int mt = 0; mt < 4; ++mt)
#pragma unroll
        for (int nt = 0; nt < 4; ++nt)
          acc[mt][nt] = mfma16(af[mt], bfv[nt], acc[mt][nt]);
    }
  }
}

// ---------------- QKV GEMM with fused RoPE+L2norm (q,k) / transpose (v) epilogue ----
__global__ __launch_bounds__(256) void gemm_qkv(
    const u16* xq, const u16* xk, const u16* xv,
    const u16* wq, const u16* wk, const u16* wv,
    const float* bq_, const float* bk_, const float* bv_,
    const float* __restrict__ cosT, const float* __restrict__ sinT,
    u16* qh, u16* kh, u16* vt) {
  int z = blockIdx.z;
  const u16* A = z == 0 ? xq : (z == 1 ? xk : xv);
  const u16* W = z == 0 ? wq : (z == 1 ? wk : wv);
  const float* bias = z == 0 ? bq_ : (z == 1 ? bk_ : bv_);
  f32x4 acc[4][4];
  gemm_main(A, W, acc);

  const int tid = threadIdx.x, lane = tid & 63, wid = tid >> 6;
  const int lr = lane & 15, lh = lane >> 4;
  const int m0 = blockIdx.x * 128, n0 = blockIdx.y * 128;
  const int wm = (wid >> 1) * 64, wn = (wid & 1) * 64;
  const int hh = (n0 + wn) >> 6;          // head (wave covers exactly one head)
  const int b = m0 >> 9;                  // 128-row block sits inside one b
  const int sbase = (m0 & 511) + wm;
  float bv[4];
#pragma unroll
  for (int nt = 0; nt < 4; ++nt) bv[nt] = bias[n0 + wn + nt * 16 + lr];

  if (z < 2) {
    // RoPE + L2-normalize each output row (d=64 within this wave), write (B,H,S,D)
    u16* dst = z ? kh : qh;
#pragma unroll
    for (int mt = 0; mt < 4; ++mt) {
#pragma unroll
      for (int i = 0; i < 4; ++i) {
        int s = sbase + mt * 16 + lh * 4 + i;
        float r[4];
        float ss = 0.f;
#pragma unroll
        for (int nt = 0; nt < 4; ++nt) {
          float t = acc[mt][nt][i] + bv[nt];
          float pr = __shfl_xor(t, 1);
          int ii = (nt * 16 + lr) >> 1;
          float c = cosT[s * 32 + ii], sn = sinT[s * 32 + ii];
          r[nt] = (lane & 1) ? (pr * sn + t * c) : (t * c - pr * sn);
          ss += r[nt] * r[nt];
        }
#pragma unroll
        for (int m = 1; m < 16; m <<= 1) ss += __shfl_xor(ss, m);
        float inv = 1.f / fmaxf(sqrtf(ss), 1e-12f);
        size_t ob = ((size_t)(b * Hh + hh) * Ss + s) * 64;
#pragma unroll
        for (int nt = 0; nt < 4; ++nt) dst[ob + nt * 16 + lr] = f2bf(r[nt] * inv);
      }
    }
  } else {
    // V: write transposed (B,H,D,S); 4 consecutive s per lane -> 8B store
#pragma unroll
    for (int mt = 0; mt < 4; ++mt) {
#pragma unroll
      for (int nt = 0; nt < 4; ++nt) {
        int d = nt * 16 + lr;
        int s4 = sbase + mt * 16 + lh * 4;
        u16x4 pv;
#pragma unroll
        for (int i = 0; i < 4; ++i) pv[i] = f2bf(acc[mt][nt][i] + bv[nt]);
        *(u16x4*)(vt + ((size_t)(b * Hh + hh) * 64 + d) * Ss + s4) = pv;
      }
    }
  }
}

// ---------------- final GEMM: fp32 out ----------------
__global__ __launch_bounds__(256) void gemm_fin(
    const u16* __restrict__ ctx, const u16* __restrict__ wo,
    const float* __restrict__ bo_, float* __restrict__ out) {
  f32x4 acc[4][4];
  gemm_main(ctx, wo, acc);
  const int tid = threadIdx.x, lane = tid & 63, wid = tid >> 6;
  const int lr = lane & 15, lh = lane >> 4;
  const int m0 = blockIdx.x * 128, n0 = blockIdx.y * 128;
  const int wm = (wid >> 1) * 64, wn = (wid & 1) * 64;
#pragma unroll
  for (int nt = 0; nt < 4; ++nt) {
    int col = n0 + wn + nt * 16 + lr;
    float bvv = bo_[col];
#pragma unroll
    for (int mt = 0; mt < 4; ++mt)
#pragma unroll
      for (int i = 0; i < 4; ++i) {
        int row = m0 + wm + mt * 16 + lh * 4 + i;
        out[(size_t)row * Ee + col] = acc[mt][nt][i] + bvv;
      }
  }
}

// ---------------- fused flash attention per (b,h,qblock) ----------------
__global__ __launch_bounds__(256) void attn_k(
    const u16* __restrict__ qh, const u16* __restrict__ kh, const u16* __restrict__ vT,
    const float* __restrict__ temp, u16* __restrict__ ctx) {
  __shared__ u16 sQ[64 * 64], sK[64 * 64], sV[64 * 64];
  __shared__ u16 sP[4][16 * 64];
  int tid = threadIdx.x, lane = tid & 63, wid = tid >> 6;
  int lr = lane & 15, lh = lane >> 4;
  int qb = blockIdx.x, h = blockIdx.y, b = blockIdx.z;
  float T = temp[0];
  size_t bh = (size_t)b * Hh + h;
  const u16* Qg = qh + (bh * Ss + qb * 64) * 64;
  const u16* Kg = kh + bh * Ss * 64;
  const u16* Vg = vT + bh * 64 * Ss;

#pragma unroll
  for (int j = 0; j < 2; ++j) {
    int c = tid + j * 256;
    int r = c >> 3, p = c & 7;
    *(u16x8*)(&sQ[r * 64 + (p ^ (r & 7)) * 8]) = *(const u16x8*)(Qg + c * 8);
  }
  __syncthreads();
  bf16x8 qf[2];
  {
    int rq = wid * 16 + lr;
    qf[0] = ldsbf8(&sQ[rq * 64 + ((0 + lh) ^ (lr & 7)) * 8]);
    qf[1] = ldsbf8(&sQ[rq * 64 + ((4 + lh) ^ (lr & 7)) * 8]);
  }
  f32x4 o[4];
#pragma unroll
  for (int nt = 0; nt < 4; ++nt) o[nt] = f32x4{0.f, 0.f, 0.f, 0.f};
  float mrow[4] = {-1e30f, -1e30f, -1e30f, -1e30f};
  float lrow[4] = {0.f, 0.f, 0.f, 0.f};
  u16* sPw = sP[wid];

  for (int kb = 0; kb < Ss / 64; ++kb) {
    __syncthreads();
    const u16* Kt = Kg + (size_t)kb * 64 * 64;
#pragma unroll
    for (int j = 0; j < 2; ++j) {
      int c = tid + j * 256;
      int r = c >> 3, p = c & 7;
      int sl = (p ^ (r & 7)) * 8;
      *(u16x8*)(&sK[r * 64 + sl]) = *(const u16x8*)(Kt + c * 8);
      *(u16x8*)(&sV[r * 64 + sl]) = *(const u16x8*)(Vg + (size_t)r * Ss + kb * 64 + p * 8);
    }
    __syncthreads();
    f32x4 sc[4];
#pragma unroll
    for (int nt = 0; nt < 4; ++nt) sc[nt] = f32x4{0.f, 0.f, 0.f, 0.f};
#pragma unroll
    for (int ks = 0; ks < 2; ++ks)
#pragma unroll
      for (int nt = 0; nt < 4; ++nt) {
        int rk = nt * 16 + lr;
        bf16x8 kf = ldsbf8(&sK[rk * 64 + ((ks * 4 + lh) ^ (lr & 7)) * 8]);
        sc[nt] = mfma16(qf[ks], kf, sc[nt]);
      }
    float mb[4], mn[4], scl[4], psum[4];
#pragma unroll
    for (int nt = 0; nt < 4; ++nt)
#pragma unroll
      for (int i = 0; i < 4; ++i) sc[nt][i] *= T;
#pragma unroll
    for (int i = 0; i < 4; ++i) {
      mb[i] = fmaxf(fmaxf(sc[0][i], sc[1][i]), fmaxf(sc[2][i], sc[3][i]));
#pragma unroll
      for (int m = 1; m < 16; m <<= 1) mb[i] = fmaxf(mb[i], __shfl_xor(mb[i], m));
      mn[i] = fmaxf(mrow[i], mb[i]);
      scl[i] = __expf(mrow[i] - mn[i]);
      psum[i] = 0.f;
    }
#pragma unroll
    for (int nt = 0; nt < 4; ++nt)
#pragma unroll
      for (int i = 0; i < 4; ++i) {
        float p = __expf(sc[nt][i] - mn[i]);
        psum[i] += p;
        int kk = nt * 16 + lr;
        int rowp = lh * 4 + i;
        sPw[rowp * 64 + ((kk >> 3) ^ (rowp & 7)) * 8 + (kk & 7)] = f2bf(p);
      }
#pragma unroll
    for (int i = 0; i < 4; ++i) {
#pragma unroll
      for (int m = 1; m < 16; m <<= 1) psum[i] += __shfl_xor(psum[i], m);
      lrow[i] = lrow[i] * scl[i] + psum[i];
      mrow[i] = mn[i];
    }
#pragma unroll
    for (int nt = 0; nt < 4; ++nt)
#pragma unroll
      for (int i = 0; i < 4; ++i) o[nt][i] *= scl[i];
    // PV
#pragma unroll
    for (int ks = 0; ks < 2; ++ks) {
      bf16x8 pf = ldsbf8(&sPw[lr * 64 + ((ks * 4 + lh) ^ (lr & 7)) * 8]);
#pragma unroll
      for (int nt = 0; nt < 4; ++nt) {
        int dv = nt * 16 + lr;
        bf16x8 vf = ldsbf8(&sV[dv * 64 + ((ks * 4 + lh) ^ (lr & 7)) * 8]);
        o[nt] = mfma16(pf, vf, o[nt]);
      }
    }
  }
#pragma unroll
  for (int nt = 0; nt < 4; ++nt) {
    int d = nt * 16 + lr;
#pragma unroll
    for (int i = 0; i < 4; ++i) {
      int row = qb * 64 + wid * 16 + lh * 4 + i;
      float val = o[nt][i] / lrow[i];
      ctx[((size_t)b * Ss + row) * Ee + h * 64 + d] = f2bf(val);
    }
  }
}

// ---------------- launcher ----------------
extern "C" void kernel_launch(void* const* d_in, const int* in_sizes, int n_in,
                              void* d_out, int out_size, void* d_ws, size_t ws_size,
                              hipStream_t stream) {
  const float* x_q = (const float*)d_in[0];
  const float* x_k = (const float*)d_in[1];
  const float* x_v = (const float*)d_in[2];
  const float* Wq = (const float*)d_in[3];
  const float* bq = (const float*)d_in[4];
  const float* Wk = (const float*)d_in[5];
  const float* bk = (const float*)d_in[6];
  const float* Wv = (const float*)d_in[7];
  const float* bv = (const float*)d_in[8];
  const float* Wo = (const float*)d_in[9];
  const float* bo = (const float*)d_in[10];
  const float* temp = (const float*)d_in[11];
  const float* cosT = (const float*)d_in[12];
  const float* sinT = (const float*)d_in[13];

  char* ws = (char*)d_ws;
  constexpr size_t MB = 1ull << 20;
  // ws layout (peak 50 MiB; round-0 run proved ws_size >= 56 MiB):
  u16* XQb = (u16*)(ws + 0 * MB);    // 8 MiB  (dead after gemm_qkv)
  u16* XKb = (u16*)(ws + 8 * MB);    // 8 MiB  (dead after gemm_qkv)
  u16* XVb = (u16*)(ws + 16 * MB);   // 8 MiB  (dead after gemm_qkv)
  u16* WOb = (u16*)(ws + 24 * MB);   // 2 MiB
  u16* QH  = (u16*)(ws + 26 * MB);   // 8 MiB  (B,H,S,D)
  u16* KH  = (u16*)(ws + 34 * MB);   // 8 MiB
  u16* VT  = (u16*)(ws + 42 * MB);   // 8 MiB  (B,H,D,S)
  u16* CTX = XKb;                    // reuse (XKb dead before attn writes)
  // Wq/Wk/Wv bf16 parked in d_out (16 MiB) — dead before gemm_fin overwrites it.
  u16* WQb = (u16*)d_out;
  u16* WKb = (u16*)((char*)d_out + 2 * MB);
  u16* WVb = (u16*)((char*)d_out + 4 * MB);

  ConvArgs ca;
  ca.s[0] = x_q; ca.s[1] = x_k; ca.s[2] = x_v;
  ca.s[3] = Wq;  ca.s[4] = Wk;  ca.s[5] = Wv; ca.s[6] = Wo;
  ca.d[0] = XQb; ca.d[1] = XKb; ca.d[2] = XVb;
  ca.d[3] = WQb; ca.d[4] = WKb; ca.d[5] = WVb; ca.d[6] = WOb;
  int nx = BS * Ee, nw = Ee * Ee;
  ca.n[0] = nx; ca.n[1] = nx; ca.n[2] = nx;
  ca.n[3] = nw; ca.n[4] = nw; ca.n[5] = nw; ca.n[6] = nw;
  convert_k<<<dim3(nx / (256 * 8), 7), 256, 0, stream>>>(ca);

  gemm_qkv<<<dim3(BS / 128, Ee / 128, 3), 256, 0, stream>>>(
      XQb, XKb, XVb, WQb, WKb, WVb, bq, bk, bv, cosT, sinT, QH, KH, VT);
  attn_k<<<dim3(Ss / 64, Hh, Bb), 256, 0, stream>>>(QH, KH, VT, temp, CTX);
  gemm_fin<<<dim3(BS / 128, Ee / 128), 256, 0, stream>>>(CTX, WOb, bo, (float*)d_out);
}

// Round 4
// 220.534 us; speedup vs baseline: 1.2880x; 1.0187x over previous
//
#include <hip/hip_runtime.h>
#include <stdint.h>

#define DEV __device__ __forceinline__

typedef __bf16 bf16x8 __attribute__((ext_vector_type(8)));
typedef float f32x4 __attribute__((ext_vector_type(4)));
typedef unsigned short u16;
typedef u16 u16x8 __attribute__((ext_vector_type(8)));
typedef u16 u16x4 __attribute__((ext_vector_type(4)));
typedef __attribute__((address_space(3))) uint8_t lds8;
typedef __attribute__((address_space(1))) const uint8_t glb8;

constexpr int Bb = 8, Ss = 512, Ee = 1024, Hh = 16;
constexpr int BS = Bb * Ss;     // 4096

DEV u16 f2bf(float f) {
  union { float f; uint32_t u; } v; v.f = f;
  return (u16)((v.u + 0x7FFFu + ((v.u >> 16) & 1u)) >> 16);
}
DEV bf16x8 ldsbf8(const u16* p) {
  u16x8 u = *(const u16x8*)p;
  return __builtin_bit_cast(bf16x8, u);
}
DEV f32x4 mfma16(bf16x8 a, bf16x8 b, f32x4 c) {
  return __builtin_amdgcn_mfma_f32_16x16x32_bf16(a, b, c, 0, 0, 0);
}

// ---------------- fp32 -> bf16 conversion (one pass for all operands) ----------------
struct ConvArgs {
  const float* s[7];
  u16* d[7];
  int n[7];
};

__global__ __launch_bounds__(256) void convert_k(ConvArgs a) {
  int z = blockIdx.y;
  int base = (blockIdx.x * 256 + threadIdx.x) * 8;
  if (base >= a.n[z]) return;
  const float4* sp = (const float4*)(a.s[z] + base);
  float4 v0 = sp[0], v1 = sp[1];
  u16x8 o;
  o[0] = f2bf(v0.x); o[1] = f2bf(v0.y); o[2] = f2bf(v0.z); o[3] = f2bf(v0.w);
  o[4] = f2bf(v1.x); o[5] = f2bf(v1.y); o[6] = f2bf(v1.z); o[7] = f2bf(v1.w);
  *(u16x8*)(a.d[z] + base) = o;
}

// ---------------- GEMM main loop: 128x128 tile, BK=32, double-buffered LDS -------
// 2-phase schedule (T3-minimum): issue STAGE(next) -> compute(cur) -> barrier.
// LDS pair-row layout: physical chunk (q, sl) [q=row-pair, sl in 0..7 of 16B]
// holds global (r = 2q + (rp>>2), p = rp&3) with rp = sl ^ (q&7). 8 consecutive
// lanes hit 8 distinct slots on frag reads -> conflict-free-ish.
DEV void gemm_main(const u16* __restrict__ A, const u16* __restrict__ W,
                   f32x4 (&acc)[4][4]) {
  constexpr int K = Ee;
  __shared__ u16 sA[2][128 * 32], sB[2][128 * 32];
  const int tid = threadIdx.x, lane = tid & 63, wid = tid >> 6;
  const int lr = lane & 15, lh = lane >> 4;
  const int m0 = blockIdx.x * 128, n0 = blockIdx.y * 128;
  const int wm = (wid >> 1) * 64, wn = (wid & 1) * 64;

  // per-lane staging sources (constant across K; add k0 per iter)
  const u16* aSrc[2]; const u16* bSrc[2]; int ldsOff[2];
#pragma unroll
  for (int j = 0; j < 2; ++j) {
    int c0 = j * 256 + wid * 64;          // wave-uniform LDS chunk base
    int c = c0 + lane;
    int q = c >> 3, sl = c & 7;
    int rp = sl ^ (q & 7);
    int r = q * 2 + (rp >> 2), p = rp & 3;
    aSrc[j] = A + (size_t)(m0 + r) * K + p * 8;
    bSrc[j] = W + (size_t)(n0 + r) * K + p * 8;
    ldsOff[j] = c0 * 8;
  }
  // frag read offsets (u16 units), constant across K
  int offA[4], offB[4];
#pragma unroll
  for (int t = 0; t < 4; ++t) {
    int ra = wm + t * 16 + lr;
    offA[t] = (ra >> 1) * 64 + ((((ra & 1) << 2) | lh) ^ ((ra >> 1) & 7)) * 8;
    int rb = wn + t * 16 + lr;
    offB[t] = (rb >> 1) * 64 + ((((rb & 1) << 2) | lh) ^ ((rb >> 1) & 7)) * 8;
  }
#pragma unroll
  for (int a = 0; a < 4; ++a)
#pragma unroll
    for (int q = 0; q < 4; ++q) acc[a][q] = f32x4{0.f, 0.f, 0.f, 0.f};

#define GSTAGE(buf, k0_)                                                       \
  {                                                                            \
    _Pragma("unroll") for (int j = 0; j < 2; ++j) {                            \
      __builtin_amdgcn_global_load_lds((glb8*)(aSrc[j] + (k0_)),               \
                                       (lds8*)&sA[buf][ldsOff[j]], 16, 0, 0);  \
      __builtin_amdgcn_global_load_lds((glb8*)(bSrc[j] + (k0_)),               \
                                       (lds8*)&sB[buf][ldsOff[j]], 16, 0, 0);  \
    }                                                                          \
  }

  GSTAGE(0, 0);
  __syncthreads();
  int cur = 0;
  for (int k0 = 0; k0 < K; k0 += 32) {
    if (k0 + 32 < K) GSTAGE(cur ^ 1, k0 + 32);   // issue-early: flies during MFMA
    bf16x8 af[4], bfv[4];
#pragma unroll
    for (int t = 0; t < 4; ++t) {
      af[t] = ldsbf8(&sA[cur][offA[t]]);
      bfv[t] = ldsbf8(&sB[cur][offB[t]]);
    }
#pragma unroll
    for (int mt = 0; mt < 4; ++mt)
#pragma unroll
      for (int nt = 0; nt < 4; ++nt)
        acc[mt][nt] = mfma16(af[mt], bfv[nt], acc[mt][nt]);
    __syncthreads();                              // single drain per K-step
    cur ^= 1;
  }
#undef GSTAGE
}

// ---------------- QKV GEMM with fused RoPE+L2norm (q,k) / transpose (v) epilogue ----
__global__ __launch_bounds__(256) void gemm_qkv(
    const u16* xq, const u16* xk, const u16* xv,
    const u16* wq, const u16* wk, const u16* wv,
    const float* bq_, const float* bk_, const float* bv_,
    const float* __restrict__ cosT, const float* __restrict__ sinT,
    u16* qh, u16* kh, u16* vt) {
  int z = blockIdx.z;
  const u16* A = z == 0 ? xq : (z == 1 ? xk : xv);
  const u16* W = z == 0 ? wq : (z == 1 ? wk : wv);
  const float* bias = z == 0 ? bq_ : (z == 1 ? bk_ : bv_);
  f32x4 acc[4][4];
  gemm_main(A, W, acc);

  const int tid = threadIdx.x, lane = tid & 63, wid = tid >> 6;
  const int lr = lane & 15, lh = lane >> 4;
  const int m0 = blockIdx.x * 128, n0 = blockIdx.y * 128;
  const int wm = (wid >> 1) * 64, wn = (wid & 1) * 64;
  const int hh = (n0 + wn) >> 6;          // head (wave covers exactly one head)
  const int b = m0 >> 9;                  // 128-row block sits inside one b
  const int sbase = (m0 & 511) + wm;
  float bv[4];
#pragma unroll
  for (int nt = 0; nt < 4; ++nt) bv[nt] = bias[n0 + wn + nt * 16 + lr];

  if (z < 2) {
    // RoPE + L2-normalize each output row (d=64 within this wave), write (B,H,S,D)
    u16* dst = z ? kh : qh;
#pragma unroll
    for (int mt = 0; mt < 4; ++mt) {
#pragma unroll
      for (int i = 0; i < 4; ++i) {
        int s = sbase + mt * 16 + lh * 4 + i;
        float r[4];
        float ss = 0.f;
#pragma unroll
        for (int nt = 0; nt < 4; ++nt) {
          float t = acc[mt][nt][i] + bv[nt];
          float pr = __shfl_xor(t, 1);
          int ii = (nt * 16 + lr) >> 1;
          float c = cosT[s * 32 + ii], sn = sinT[s * 32 + ii];
          r[nt] = (lane & 1) ? (pr * sn + t * c) : (t * c - pr * sn);
          ss += r[nt] * r[nt];
        }
#pragma unroll
        for (int m = 1; m < 16; m <<= 1) ss += __shfl_xor(ss, m);
        float inv = 1.f / fmaxf(sqrtf(ss), 1e-12f);
        size_t ob = ((size_t)(b * Hh + hh) * Ss + s) * 64;
#pragma unroll
        for (int nt = 0; nt < 4; ++nt) dst[ob + nt * 16 + lr] = f2bf(r[nt] * inv);
      }
    }
  } else {
    // V: write transposed (B,H,D,S); 4 consecutive s per lane -> 8B store
#pragma unroll
    for (int mt = 0; mt < 4; ++mt) {
#pragma unroll
      for (int nt = 0; nt < 4; ++nt) {
        int d = nt * 16 + lr;
        int s4 = sbase + mt * 16 + lh * 4;
        u16x4 pv;
#pragma unroll
        for (int i = 0; i < 4; ++i) pv[i] = f2bf(acc[mt][nt][i] + bv[nt]);
        *(u16x4*)(vt + ((size_t)(b * Hh + hh) * 64 + d) * Ss + s4) = pv;
      }
    }
  }
}

// ---------------- final GEMM: fp32 out ----------------
__global__ __launch_bounds__(256) void gemm_fin(
    const u16* __restrict__ ctx, const u16* __restrict__ wo,
    const float* __restrict__ bo_, float* __restrict__ out) {
  f32x4 acc[4][4];
  gemm_main(ctx, wo, acc);
  const int tid = threadIdx.x, lane = tid & 63, wid = tid >> 6;
  const int lr = lane & 15, lh = lane >> 4;
  const int m0 = blockIdx.x * 128, n0 = blockIdx.y * 128;
  const int wm = (wid >> 1) * 64, wn = (wid & 1) * 64;
#pragma unroll
  for (int nt = 0; nt < 4; ++nt) {
    int col = n0 + wn + nt * 16 + lr;
    float bvv = bo_[col];
#pragma unroll
    for (int mt = 0; mt < 4; ++mt)
#pragma unroll
      for (int i = 0; i < 4; ++i) {
        int row = m0 + wm + mt * 16 + lh * 4 + i;
        out[(size_t)row * Ee + col] = acc[mt][nt][i] + bvv;
      }
  }
}

// ---------------- fused flash attention per (b,h,qblock) ----------------
// K/V double-buffered, staged via global_load_lds (pre-swizzled source),
// ONE barrier per kv-tile; setprio around MFMA clusters.
__global__ __launch_bounds__(256) void attn_k(
    const u16* __restrict__ qh, const u16* __restrict__ kh, const u16* __restrict__ vT,
    const float* __restrict__ temp, u16* __restrict__ ctx) {
  __shared__ u16 sQ[64 * 64], sK[2][64 * 64], sV[2][64 * 64];
  __shared__ u16 sP[4][16 * 64];
  int tid = threadIdx.x, lane = tid & 63, wid = tid >> 6;
  int lr = lane & 15, lh = lane >> 4;
  int qb = blockIdx.x, h = blockIdx.y, b = blockIdx.z;
  float T = temp[0];
  size_t bh = (size_t)b * Hh + h;
  const u16* Qg = qh + (bh * Ss + qb * 64) * 64;
  const u16* Kg = kh + bh * Ss * 64;
  const u16* Vg = vT + bh * 64 * Ss;

  // staging maps (row-major 64x(64d) tiles, 8-slot XOR swizzle)
  const u16* qSrc[2]; const u16* kSrc[2]; const u16* vSrc[2]; int soff[2];
#pragma unroll
  for (int j = 0; j < 2; ++j) {
    int c0 = j * 256 + wid * 64;
    int c = c0 + lane;
    int r = c >> 3, p = (c & 7) ^ (r & 7);
    soff[j] = c0 * 8;
    qSrc[j] = Qg + r * 64 + p * 8;
    kSrc[j] = Kg + r * 64 + p * 8;            // + kb*4096
    vSrc[j] = Vg + (size_t)r * Ss + p * 8;    // + kb*64
  }
#define ASTAGE(buf, kb_)                                                        \
  {                                                                             \
    _Pragma("unroll") for (int j = 0; j < 2; ++j) {                             \
      __builtin_amdgcn_global_load_lds((glb8*)(kSrc[j] + (kb_) * 4096),         \
                                       (lds8*)&sK[buf][soff[j]], 16, 0, 0);     \
      __builtin_amdgcn_global_load_lds((glb8*)(vSrc[j] + (kb_) * 64),           \
                                       (lds8*)&sV[buf][soff[j]], 16, 0, 0);     \
    }                                                                           \
  }

#pragma unroll
  for (int j = 0; j < 2; ++j)
    __builtin_amdgcn_global_load_lds((glb8*)qSrc[j], (lds8*)&sQ[soff[j]], 16, 0, 0);
  ASTAGE(0, 0);
  __syncthreads();

  bf16x8 qf[2];
  {
    int rq = wid * 16 + lr;
    qf[0] = ldsbf8(&sQ[rq * 64 + ((0 + lh) ^ (lr & 7)) * 8]);
    qf[1] = ldsbf8(&sQ[rq * 64 + ((4 + lh) ^ (lr & 7)) * 8]);
  }
  f32x4 o[4];
#pragma unroll
  for (int nt = 0; nt < 4; ++nt) o[nt] = f32x4{0.f, 0.f, 0.f, 0.f};
  float mrow[4] = {-1e30f, -1e30f, -1e30f, -1e30f};
  float lrow[4] = {0.f, 0.f, 0.f, 0.f};
  u16* sPw = sP[wid];
  int cur = 0;

  for (int kb = 0; kb < Ss / 64; ++kb) {
    if (kb + 1 < Ss / 64) ASTAGE(cur ^ 1, kb + 1);   // flies during compute
    f32x4 sc[4];
#pragma unroll
    for (int nt = 0; nt < 4; ++nt) sc[nt] = f32x4{0.f, 0.f, 0.f, 0.f};
    __builtin_amdgcn_s_setprio(1);
#pragma unroll
    for (int ks = 0; ks < 2; ++ks)
#pragma unroll
      for (int nt = 0; nt < 4; ++nt) {
        int rk = nt * 16 + lr;
        bf16x8 kf = ldsbf8(&sK[cur][rk * 64 + ((ks * 4 + lh) ^ (lr & 7)) * 8]);
        sc[nt] = mfma16(qf[ks], kf, sc[nt]);
      }
    __builtin_amdgcn_s_setprio(0);
    float mb[4], mn[4], scl[4], psum[4];
#pragma unroll
    for (int nt = 0; nt < 4; ++nt)
#pragma unroll
      for (int i = 0; i < 4; ++i) sc[nt][i] *= T;
#pragma unroll
    for (int i = 0; i < 4; ++i) {
      mb[i] = fmaxf(fmaxf(sc[0][i], sc[1][i]), fmaxf(sc[2][i], sc[3][i]));
#pragma unroll
      for (int m = 1; m < 16; m <<= 1) mb[i] = fmaxf(mb[i], __shfl_xor(mb[i], m));
      mn[i] = fmaxf(mrow[i], mb[i]);
      scl[i] = __expf(mrow[i] - mn[i]);
      psum[i] = 0.f;
    }
#pragma unroll
    for (int nt = 0; nt < 4; ++nt)
#pragma unroll
      for (int i = 0; i < 4; ++i) {
        float p = __expf(sc[nt][i] - mn[i]);
        psum[i] += p;
        int kk = nt * 16 + lr;
        int rowp = lh * 4 + i;
        sPw[rowp * 64 + ((kk >> 3) ^ (rowp & 7)) * 8 + (kk & 7)] = f2bf(p);
      }
#pragma unroll
    for (int i = 0; i < 4; ++i) {
#pragma unroll
      for (int m = 1; m < 16; m <<= 1) psum[i] += __shfl_xor(psum[i], m);
      lrow[i] = lrow[i] * scl[i] + psum[i];
      mrow[i] = mn[i];
    }
#pragma unroll
    for (int nt = 0; nt < 4; ++nt)
#pragma unroll
      for (int i = 0; i < 4; ++i) o[nt][i] *= scl[i];
    // PV
    __builtin_amdgcn_s_setprio(1);
#pragma unroll
    for (int ks = 0; ks < 2; ++ks) {
      bf16x8 pf = ldsbf8(&sPw[lr * 64 + ((ks * 4 + lh) ^ (lr & 7)) * 8]);
#pragma unroll
      for (int nt = 0; nt < 4; ++nt) {
        int dv = nt * 16 + lr;
        bf16x8 vf = ldsbf8(&sV[cur][dv * 64 + ((ks * 4 + lh) ^ (lr & 7)) * 8]);
        o[nt] = mfma16(pf, vf, o[nt]);
      }
    }
    __builtin_amdgcn_s_setprio(0);
    __syncthreads();   // drains this iter's prefetch; next tile ready
    cur ^= 1;
  }
#undef ASTAGE
#pragma unroll
  for (int nt = 0; nt < 4; ++nt) {
    int d = nt * 16 + lr;
#pragma unroll
    for (int i = 0; i < 4; ++i) {
      int row = qb * 64 + wid * 16 + lh * 4 + i;
      float val = o[nt][i] / lrow[i];
      ctx[((size_t)b * Ss + row) * Ee + h * 64 + d] = f2bf(val);
    }
  }
}

// ---------------- launcher ----------------
extern "C" void kernel_launch(void* const* d_in, const int* in_sizes, int n_in,
                              void* d_out, int out_size, void* d_ws, size_t ws_size,
                              hipStream_t stream) {
  const float* x_q = (const float*)d_in[0];
  const float* x_k = (const float*)d_in[1];
  const float* x_v = (const float*)d_in[2];
  const float* Wq = (const float*)d_in[3];
  const float* bq = (const float*)d_in[4];
  const float* Wk = (const float*)d_in[5];
  const float* bk = (const float*)d_in[6];
  const float* Wv = (const float*)d_in[7];
  const float* bv = (const float*)d_in[8];
  const float* Wo = (const float*)d_in[9];
  const float* bo = (const float*)d_in[10];
  const float* temp = (const float*)d_in[11];
  const float* cosT = (const float*)d_in[12];
  const float* sinT = (const float*)d_in[13];

  char* ws = (char*)d_ws;
  constexpr size_t MB = 1ull << 20;
  u16* XQb = (u16*)(ws + 0 * MB);    // 8 MiB  (dead after gemm_qkv)
  u16* XKb = (u16*)(ws + 8 * MB);    // 8 MiB  (dead after gemm_qkv)
  u16* XVb = (u16*)(ws + 16 * MB);   // 8 MiB  (dead after gemm_qkv)
  u16* WOb = (u16*)(ws + 24 * MB);   // 2 MiB
  u16* QH  = (u16*)(ws + 26 * MB);   // 8 MiB  (B,H,S,D)
  u16* KH  = (u16*)(ws + 34 * MB);   // 8 MiB
  u16* VT  = (u16*)(ws + 42 * MB);   // 8 MiB  (B,H,D,S)
  u16* CTX = XKb;                    // reuse (XKb dead before attn writes)
  u16* WQb = (u16*)d_out;            // parked in d_out, dead before gemm_fin
  u16* WKb = (u16*)((char*)d_out + 2 * MB);
  u16* WVb = (u16*)((char*)d_out + 4 * MB);

  ConvArgs ca;
  ca.s[0] = x_q; ca.s[1] = x_k; ca.s[2] = x_v;
  ca.s[3] = Wq;  ca.s[4] = Wk;  ca.s[5] = Wv; ca.s[6] = Wo;
  ca.d[0] = XQb; ca.d[1] = XKb; ca.d[2] = XVb;
  ca.d[3] = WQb; ca.d[4] = WKb; ca.d[5] = WVb; ca.d[6] = WOb;
  int nx = BS * Ee, nw = Ee * Ee;
  ca.n[0] = nx; ca.n[1] = nx; ca.n[2] = nx;
  ca.n[3] = nw; ca.n[4] = nw; ca.n[5] = nw; ca.n[6] = nw;
  convert_k<<<dim3(nx / (256 * 8), 7), 256, 0, stream>>>(ca);

  gemm_qkv<<<dim3(BS / 128, Ee / 128, 3), 256, 0, stream>>>(
      XQb, XKb, XVb, WQb, WKb, WVb, bq, bk, bv, cosT, sinT, QH, KH, VT);
  attn_k<<<dim3(Ss / 64, Hh, Bb), 256, 0, stream>>>(QH, KH, VT, temp, CTX);
  gemm_fin<<<dim3(BS / 128, Ee / 128), 256, 0, stream>>>(CTX, WOb, bo, (float*)d_out);
}